// Round 21
// baseline (116.932 us; speedup 1.0000x reference)
//
#include <hip/hip_runtime.h>
#include <hip/hip_bf16.h>

// ---- problem constants ----
constexpr int N0 = 400000, N1 = 75000, N2 = 15000;
constexpr int E1 = 1200000, E2 = 240000;
constexpr int NC = 40;
constexpr float NEG_SLOPE = 0.2f;

// buckets (aggregation granularity)
constexpr int BK1 = 128;                     // dst nodes per bucket, layer 1
constexpr int NB1 = (N1 + BK1 - 1) / BK1;    // 586
constexpr int CAPB1 = 2432;                  // per-bucket total cap (mean 2048, +8.5 sigma)
constexpr int BK2 = 32;                      // dst nodes per bucket, layer 2
constexpr int NB2 = (N2 + BK2 - 1) / BK2;    // 469
constexpr int CAPB2 = 704;                   // mean 512, +8.5 sigma

// single-pass tile-private binning
constexpr int TILE = 4096;                   // edges per binning block
constexpr int NT1L = (E1 + TILE - 1) / TILE; // 293
constexpr int NT2L = (E2 + TILE - 1) / TILE; // 59
constexpr int NTB = NT1L + NT2L;             // 352 binning blocks
constexpr int SUBCAP = 32;                   // per (tile,bucket) cap
constexpr int BPJ = N0 / 128;                // 3125 projection blocks (128 nodes each)

using f32x4 = __attribute__((ext_vector_type(4))) float;
using s16x8 = __attribute__((ext_vector_type(8))) short;   // 8 bf16 (4 VGPRs)

__device__ __forceinline__ float leaky(float v) { return v > 0.f ? v : NEG_SLOPE * v; }

// v_cvt_pk_bf16_f32: D[15:0]=bf16(lo), D[31:16]=bf16(hi) (no builtin on gfx950)
__device__ __forceinline__ unsigned cvtpk(float lo, float hi) {
    unsigned r;
    asm("v_cvt_pk_bf16_f32 %0, %1, %2" : "=v"(r) : "v"(lo), "v"(hi));
    return r;
}

// RNE pack of two floats into a bf16x2 word (VALU fallback, cold paths)
__device__ __forceinline__ unsigned bf16pair(float lo, float hi) {
    unsigned a = __float_as_uint(lo), b = __float_as_uint(hi);
    a = (a + 0x7FFFu + ((a >> 16) & 1u)) >> 16;
    b = (b + 0x7FFFu + ((b >> 16) & 1u)) & 0xFFFF0000u;
    return a | b;
}
__device__ __forceinline__ float bfLo(unsigned w) { return __uint_as_float(w << 16); }
__device__ __forceinline__ float bfHi(unsigned w) { return __uint_as_float(w & 0xFFFF0000u); }

// ============ K1: single-pass binning + MFMA projection (32 nodes / wave) ============
// rec1[node] (16 words, 64B): w0..w7 bf16x2 hs1, w8/w9 fp32 a_s; w10..15 pad
__global__ __launch_bounds__(256, 4) void k1_kernel(
    const float* __restrict__ x,
    const float* __restrict__ W1s, const float* __restrict__ W1d,
    const float* __restrict__ att1s, const float* __restrict__ att1d,
    const int* __restrict__ e1s, const int* __restrict__ e1d,
    const int* __restrict__ e2s, const int* __restrict__ e2d,
    unsigned* __restrict__ rec1, float* __restrict__ a_d1,
    int* __restrict__ gcnt1, unsigned* __restrict__ bin1,
    int* __restrict__ gcnt2, unsigned* __restrict__ bin2)
{
    __shared__ int cur[NB1];                   // binning blocks only (NB1 >= NB2)
    __shared__ float2 vds[64];                 // proj blocks touching N1 only

    int bid = blockIdx.x;
    const int tid = threadIdx.x;
    if (bid < NTB) {
        // ---- binning: ONE pass, tile-private sub-bins, no global atomics ----
        const bool isL1 = bid < NT1L;
        const int t = isL1 ? bid : bid - NT1L;
        const int* es = isL1 ? e1s : e2s;
        const int* ed = isL1 ? e1d : e2d;
        const int nE = isL1 ? E1 : E2;
        const int nb = isL1 ? NB1 : NB2;
        const int shift = isL1 ? 7 : 5;        // log2(BK)
        const int lsh = isL1 ? 19 : 17;        // local-dst shift in payload
        int* gc = isL1 ? gcnt1 : gcnt2;
        unsigned* gbin = isL1 ? bin1 : bin2;
        const int base = t * TILE;
        const int lim = min(TILE, nE - base);

        for (int b = tid; b < nb; b += 256) cur[b] = 0;
        __syncthreads();
        for (int i = tid; i < lim; i += 256) {
            int s = es[base + i], d = ed[base + i];
            if (s != d) {                      // remove_self_loops
                int b = d >> shift;
                int pos = atomicAdd(&cur[b], 1);
                if (pos < SUBCAP)
                    gbin[((size_t)t * nb + b) * SUBCAP + pos] =
                        (unsigned)s | ((unsigned)(d & ((1 << shift) - 1)) << lsh);
            }
        }
        __syncthreads();
        for (int b = tid; b < nb; b += 256)    // plain stores, coalesced
            gc[(size_t)t * nb + b] = min(cur[b], SUBCAP);
        return;
    }
    // ---- MFMA projection: TWO 16-node tiles per wave (2x memory ILP) ----
    bid -= NTB;
    const int l  = tid & 63;
    const int nd = l & 15;           // node within tile (D col)
    const int kg = l >> 4;           // k-group / channel quad
    const int wv = tid >> 6;
    const int nodeBase = bid * 128;
    const bool hasN1 = nodeBase < N1;

    if (hasN1) {                     // vd (att1d folded into W1d) -> LDS
        if (tid < 64) {
            float d0 = 0.f, d1 = 0.f;
            const float* wr = W1d + (size_t)tid * 16;
            #pragma unroll
            for (int cc = 0; cc < 8; ++cc) {
                d0 = fmaf(wr[cc], att1d[cc], d0);
                d1 = fmaf(wr[8 + cc], att1d[8 + cc], d1);
            }
            vds[tid] = make_float2(d0, d1);
        }
        __syncthreads();
    }

    const int nodeA = nodeBase + wv * 32 + nd;
    const int nodeB = nodeA + 16;

    // issue ALL EIGHT x-row loads first; sched_barrier pins them above compute
    const float* xa = x + (size_t)nodeA * 64 + 8 * kg;
    const float* xb = x + (size_t)nodeB * 64 + 8 * kg;
    float4 qa0 = *(const float4*)(xa);
    float4 qa1 = *(const float4*)(xa + 4);
    float4 qa2 = *(const float4*)(xa + 32);
    float4 qa3 = *(const float4*)(xa + 36);
    float4 qb0 = *(const float4*)(xb);
    float4 qb1 = *(const float4*)(xb + 4);
    float4 qb2 = *(const float4*)(xb + 32);
    float4 qb3 = *(const float4*)(xb + 36);
    __builtin_amdgcn_sched_barrier(0);         // loads cannot sink below here

    // W1s fragment: lane holds W[k=(8kg..)+j][col=nd] (L1-hot, amortized over 32 nodes)
    s16x8 bf0, bf1;
    {
        union { unsigned u[4]; s16x8 v; } t0, t1;
        #pragma unroll
        for (int q = 0; q < 4; ++q) {
            t0.u[q] = cvtpk(W1s[(8 * kg + 2 * q) * 16 + nd],
                            W1s[(8 * kg + 2 * q + 1) * 16 + nd]);
            t1.u[q] = cvtpk(W1s[(32 + 8 * kg + 2 * q) * 16 + nd],
                            W1s[(32 + 8 * kg + 2 * q + 1) * 16 + nd]);
        }
        bf0 = t0.v; bf1 = t1.v;
    }
    float att4[4];
    #pragma unroll
    for (int r = 0; r < 4; ++r) att4[r] = att1s[4 * kg + r];

    // ---- tile A ----
    union { unsigned u[4]; s16x8 v; } a0, a1;
    a0.u[0] = cvtpk(qa0.x, qa0.y); a0.u[1] = cvtpk(qa0.z, qa0.w);
    a0.u[2] = cvtpk(qa1.x, qa1.y); a0.u[3] = cvtpk(qa1.z, qa1.w);
    a1.u[0] = cvtpk(qa2.x, qa2.y); a1.u[1] = cvtpk(qa2.z, qa2.w);
    a1.u[2] = cvtpk(qa3.x, qa3.y); a1.u[3] = cvtpk(qa3.z, qa3.w);
    f32x4 accA = {0.f, 0.f, 0.f, 0.f};
    accA = __builtin_amdgcn_mfma_f32_16x16x32_bf16(bf0, a0.v, accA, 0, 0, 0);
    accA = __builtin_amdgcn_mfma_f32_16x16x32_bf16(bf1, a1.v, accA, 0, 0, 0);

    // ---- tile B ----
    union { unsigned u[4]; s16x8 v; } b0, b1;
    b0.u[0] = cvtpk(qb0.x, qb0.y); b0.u[1] = cvtpk(qb0.z, qb0.w);
    b0.u[2] = cvtpk(qb1.x, qb1.y); b0.u[3] = cvtpk(qb1.z, qb1.w);
    b1.u[0] = cvtpk(qb2.x, qb2.y); b1.u[1] = cvtpk(qb2.z, qb2.w);
    b1.u[2] = cvtpk(qb3.x, qb3.y); b1.u[3] = cvtpk(qb3.z, qb3.w);
    f32x4 accB = {0.f, 0.f, 0.f, 0.f};
    accB = __builtin_amdgcn_mfma_f32_16x16x32_bf16(bf0, b0.v, accB, 0, 0, 0);
    accB = __builtin_amdgcn_mfma_f32_16x16x32_bf16(bf1, b1.v, accB, 0, 0, 0);

    // ---- epilogues (A then B) ----
    {
        float p = accA[0] * att4[0];
        p = fmaf(accA[1], att4[1], p);
        p = fmaf(accA[2], att4[2], p);
        p = fmaf(accA[3], att4[3], p);
        p += __shfl_xor(p, 16, 64);
        float q = __shfl_xor(p, 32, 64);
        unsigned* rp = rec1 + (size_t)nodeA * 16;
        uint2 hw; hw.x = cvtpk(accA[0], accA[1]); hw.y = cvtpk(accA[2], accA[3]);
        *(uint2*)(rp + 2 * kg) = hw;
        if (kg == 0)
            *(uint4*)(rp + 8) = make_uint4(__float_as_uint(p), __float_as_uint(q), 0u, 0u);
        else if (kg == 1)
            *(uint4*)(rp + 12) = make_uint4(0u, 0u, 0u, 0u);
    }
    {
        float p = accB[0] * att4[0];
        p = fmaf(accB[1], att4[1], p);
        p = fmaf(accB[2], att4[2], p);
        p = fmaf(accB[3], att4[3], p);
        p += __shfl_xor(p, 16, 64);
        float q = __shfl_xor(p, 32, 64);
        unsigned* rp = rec1 + (size_t)nodeB * 16;
        uint2 hw; hw.x = cvtpk(accB[0], accB[1]); hw.y = cvtpk(accB[2], accB[3]);
        *(uint2*)(rp + 2 * kg) = hw;
        if (kg == 0)
            *(uint4*)(rp + 8) = make_uint4(__float_as_uint(p), __float_as_uint(q), 0u, 0u);
        else if (kg == 1)
            *(uint4*)(rp + 12) = make_uint4(0u, 0u, 0u, 0u);
    }

    if (hasN1) {                               // a_d1 = x . vd for nodes < N1
        if (nodeA < N1) {
            float xv8[16] = {qa0.x, qa0.y, qa0.z, qa0.w, qa1.x, qa1.y, qa1.z, qa1.w,
                             qa2.x, qa2.y, qa2.z, qa2.w, qa3.x, qa3.y, qa3.z, qa3.w};
            float pd0 = 0.f, pd1 = 0.f;
            #pragma unroll
            for (int j = 0; j < 8; ++j) {
                float2 v = vds[8 * kg + j];
                pd0 = fmaf(xv8[j], v.x, pd0);
                pd1 = fmaf(xv8[j], v.y, pd1);
            }
            #pragma unroll
            for (int j = 0; j < 8; ++j) {
                float2 v = vds[32 + 8 * kg + j];
                pd0 = fmaf(xv8[8 + j], v.x, pd0);
                pd1 = fmaf(xv8[8 + j], v.y, pd1);
            }
            pd0 += __shfl_xor(pd0, 16, 64); pd0 += __shfl_xor(pd0, 32, 64);
            pd1 += __shfl_xor(pd1, 16, 64); pd1 += __shfl_xor(pd1, 32, 64);
            if (kg == 0) ((float2*)a_d1)[nodeA] = make_float2(pd0, pd1);
        }
        if (nodeB < N1) {
            float xv8[16] = {qb0.x, qb0.y, qb0.z, qb0.w, qb1.x, qb1.y, qb1.z, qb1.w,
                             qb2.x, qb2.y, qb2.z, qb2.w, qb3.x, qb3.y, qb3.z, qb3.w};
            float pd0 = 0.f, pd1 = 0.f;
            #pragma unroll
            for (int j = 0; j < 8; ++j) {
                float2 v = vds[8 * kg + j];
                pd0 = fmaf(xv8[j], v.x, pd0);
                pd1 = fmaf(xv8[j], v.y, pd1);
            }
            #pragma unroll
            for (int j = 0; j < 8; ++j) {
                float2 v = vds[32 + 8 * kg + j];
                pd0 = fmaf(xv8[8 + j], v.x, pd0);
                pd1 = fmaf(xv8[8 + j], v.y, pd1);
            }
            pd0 += __shfl_xor(pd0, 16, 64); pd0 += __shfl_xor(pd0, 32, 64);
            pd1 += __shfl_xor(pd1, 16, 64); pd1 += __shfl_xor(pd1, 32, 64);
            if (kg == 0) ((float2*)a_d1)[nodeB] = make_float2(pd0, pd1);
        }
    }
}

// ============ K2: sort + QUAD-CHAIN node-major aggregate + fused proj2 ============
// rec2[node] (24 words, 96B): w0..w19 bf16x2 hs2, w20 a_s2, w21 a_d2
__global__ __launch_bounds__(512) void k2_kernel(
    const int* __restrict__ gcnt1, const unsigned* __restrict__ bin1,
    const unsigned* __restrict__ rec1, const float* __restrict__ a_d1,
    const float* __restrict__ b1,
    const float* __restrict__ W2s, const float* __restrict__ W2d,
    const float* __restrict__ att2s, const float* __restrict__ att2d,
    unsigned* __restrict__ rec2)
{
    __shared__ unsigned raw[CAPB1];
    __shared__ unsigned srt[CAPB1];
    __shared__ int cnts[NT1L], pfx[NT1L + 1];
    __shared__ int hist[BK1], start[BK1 + 1];
    __shared__ float w2sl[640], va[16], vd[16];
    __shared__ float h1s[BK1][17];

    const int b = blockIdx.x, tid = threadIdx.x;
    const int d0 = b * BK1;
    const int nN = min(BK1, N1 - d0);

    for (int i = tid; i < 640; i += 512) w2sl[i] = W2s[i];
    if (tid < BK1) hist[tid] = 0;
    if (tid >= 128 && tid < 144) {            // fold att2 into W2 columns
        int k = tid - 128;
        float sa = 0.f, sd = 0.f;
        for (int cc = 0; cc < 40; ++cc) {
            sa = fmaf(W2s[k * 40 + cc], att2s[cc], sa);
            sd = fmaf(W2d[k * 40 + cc], att2d[cc], sd);
        }
        va[k] = sa; vd[k] = sd;
    }
    for (int i = tid; i < NT1L; i += 512) cnts[i] = gcnt1[(size_t)i * NB1 + b];
    __syncthreads();
    // exclusive scan over 293 tile counts (wave 0, shfl_up)
    if (tid < 64) {
        int carry = 0;
        #pragma unroll
        for (int s = 0; s < (NT1L + 63) / 64; ++s) {
            int idx = s * 64 + tid;
            int v = (idx < NT1L) ? cnts[idx] : 0;
            int xv = v;
            #pragma unroll
            for (int d = 1; d < 64; d <<= 1) {
                int t2 = __shfl_up(xv, d, 64);
                if (tid >= d) xv += t2;
            }
            if (idx < NT1L) pfx[idx] = carry + xv - v;
            carry += __shfl(xv, 63, 64);
        }
        if (tid == 0) pfx[NT1L] = carry;
    }
    __syncthreads();
    // gather chunks -> raw, histogram by local dst
    for (int j = tid; j < NT1L * SUBCAP; j += 512) {
        int t = j >> 5, p = j & (SUBCAP - 1);
        if (p < cnts[t]) {
            int dst = pfx[t] + p;
            if (dst < CAPB1) {
                unsigned pay = bin1[((size_t)t * NB1 + b) * SUBCAP + p];
                raw[dst] = pay;
                atomicAdd(&hist[pay >> 19], 1);
            }
        }
    }
    __syncthreads();
    if (tid == 0) {
        int a = 0;
        for (int k = 0; k < BK1; ++k) { start[k] = a; a += hist[k]; }
        start[BK1] = a;
    }
    __syncthreads();
    if (tid < BK1) hist[tid] = start[tid];    // cursor
    __syncthreads();
    const int total = min(pfx[NT1L], CAPB1);
    for (int i = tid; i < total; i += 512) {
        unsigned p = raw[i];
        int pos = atomicAdd(&hist[p >> 19], 1);
        srt[pos] = p & 0x7FFFFu;
    }
    __syncthreads();

    // ---- QUAD-CHAIN aggregation: group g handles nodes g, g+32, g+64, g+96 ----
    const int g = tid >> 4, c = tid & 15, h = c >> 3;
    const int wbase = tid & 48;
    const int wmap = (c < 8) ? c : (8 + ((c >> 2) & 1));
    {
        int   nI[4], stI[4], cnI[4];
        float adI[4];
        #pragma unroll
        for (int q = 0; q < 4; ++q) {
            int n = g + 32 * q;
            bool v = n < nN;
            nI[q]  = d0 + (v ? n : 0);
            stI[q] = v ? start[n] : 0;
            cnI[q] = v ? (start[n + 1] - stI[q]) : -1;
            adI[q] = a_d1[(size_t)nI[q] * 2 + h];
        }
        unsigned rw0[4], rw1[4], rw2[4];
        #pragma unroll
        for (int q = 0; q < 4; ++q) {
            rw0[q] = rec1[(size_t)nI[q] * 16 + wmap];                      // self
            rw1[q] = (cnI[q] >= 1) ? rec1[(size_t)srt[stI[q]] * 16 + wmap] : 0u;
            rw2[q] = (cnI[q] >= 2) ? rec1[(size_t)srt[stI[q] + 1] * 16 + wmap] : 0u;
        }
        float acc[4] = {0.f, 0.f, 0.f, 0.f}, den[4] = {0.f, 0.f, 0.f, 0.f};
        const int mx = max(max(cnI[0], cnI[1]), max(cnI[2], cnI[3]));
        for (int j = 0; j <= mx; ++j) {
            #pragma unroll
            for (int q = 0; q < 4; ++q) {
                float asv = __uint_as_float((unsigned)__shfl((int)rw0[q], wbase + 8 + 4 * h, 64));
                unsigned chw = (unsigned)__shfl((int)rw0[q], wbase + (c >> 1), 64);
                float hv = (c & 1) ? bfHi(chw) : bfLo(chw);
                float w = (j <= cnI[q]) ? __expf(leaky(asv + adI[q])) : 0.f;
                acc[q] = fmaf(w, hv, acc[q]);
                den[q] += w;
                rw0[q] = rw1[q]; rw1[q] = rw2[q];
                rw2[q] = (j + 3 <= cnI[q]) ? rec1[(size_t)srt[stI[q] + j + 2] * 16 + wmap] : 0u;
            }
        }
        #pragma unroll
        for (int q = 0; q < 4; ++q) {
            int n = g + 32 * q;
            if (n < nN) {
                float v = acc[q] / den[q] + b1[c];
                h1s[n][c] = v > 0.f ? v : (__expf(v) - 1.f);    // ELU
            }
        }
    }
    __syncthreads();
    // fused proj2 -> rec2
    for (int i = tid; i < nN * 24; i += 512) {
        int nn = i / 24, w = i - nn * 24;
        unsigned* rp = rec2 + (size_t)(d0 + nn) * 24;
        if (w < 20) {
            int c0 = 2 * w, c1 = c0 + 1;
            float s0 = 0.f, s1 = 0.f;
            #pragma unroll
            for (int k = 0; k < 16; ++k) {
                float hk = h1s[nn][k];
                s0 = fmaf(hk, w2sl[k * 40 + c0], s0);
                s1 = fmaf(hk, w2sl[k * 40 + c1], s1);
            }
            rp[w] = bf16pair(s0, s1);
        } else if (w < 22) {
            const float* vv = (w == 20) ? va : vd;
            float s = 0.f;
            #pragma unroll
            for (int k = 0; k < 16; ++k) s = fmaf(h1s[nn][k], vv[k], s);
            rp[w] = __float_as_uint(s);
        }
    }
}

// ============ K3: gather tile-chunks + sort + 32-lane-group aggregate + log_softmax ============
__global__ __launch_bounds__(1024) void k3_kernel(
    const int* __restrict__ gcnt2, const unsigned* __restrict__ bin2,
    const unsigned* __restrict__ rec2, const float* __restrict__ b2,
    float* __restrict__ out)
{
    __shared__ unsigned raw[CAPB2];
    __shared__ unsigned srt[CAPB2];
    __shared__ int cnts[NT2L], pfx[NT2L + 1];
    __shared__ int hist[BK2], start[BK2 + 1];

    const int b = blockIdx.x, tid = threadIdx.x;
    const int d0 = b * BK2;
    const int nN = min(BK2, N2 - d0);

    if (tid < BK2) hist[tid] = 0;
    if (tid < NT2L) cnts[tid] = gcnt2[(size_t)tid * NB2 + b];
    __syncthreads();
    if (tid < 64) {                            // scan over 59 counts (one wave)
        int v = (tid < NT2L) ? cnts[tid] : 0;
        int xv = v;
        #pragma unroll
        for (int d = 1; d < 64; d <<= 1) {
            int t2 = __shfl_up(xv, d, 64);
            if (tid >= d) xv += t2;
        }
        if (tid < NT2L) pfx[tid] = xv - v;
        if (tid == NT2L - 1) pfx[NT2L] = xv;
    }
    __syncthreads();
    for (int j = tid; j < NT2L * SUBCAP; j += 1024) {
        int t = j >> 5, p = j & (SUBCAP - 1);
        if (p < cnts[t]) {
            int dst = pfx[t] + p;
            if (dst < CAPB2) {
                unsigned pay = bin2[((size_t)t * NB2 + b) * SUBCAP + p];
                raw[dst] = pay;
                atomicAdd(&hist[pay >> 17], 1);
            }
        }
    }
    __syncthreads();
    if (tid == 0) {
        int a = 0;
        for (int k = 0; k < BK2; ++k) { start[k] = a; a += hist[k]; }
        start[BK2] = a;
    }
    __syncthreads();
    if (tid < BK2) hist[tid] = start[tid];
    __syncthreads();
    const int total = min(pfx[NT2L], CAPB2);
    for (int i = tid; i < total; i += 1024) {
        unsigned p = raw[i];
        int pos = atomicAdd(&hist[p >> 17], 1);
        srt[pos] = p & 0x1FFFFu;
    }
    __syncthreads();

    // 32 groups of 32 lanes; lane l holds record word l (channels 2l,2l+1 for l<20)
    const int g = tid >> 5, l = tid & 31;
    const float bb0 = (l < 20) ? b2[2 * l] : 0.f;
    const float bb1 = (l < 20) ? b2[2 * l + 1] : 0.f;
    for (int n = g; n < nN; n += 32) {
        const int node = d0 + n;
        const int st = start[n], cnt = start[n + 1] - start[n];
        unsigned rw0 = (l < 22) ? rec2[(size_t)node * 24 + l] : 0u;          // self
        const float ad = __uint_as_float((unsigned)__shfl((int)rw0, 21, 32));
        unsigned rw1 = (cnt >= 1 && l < 21) ? rec2[(size_t)srt[st] * 24 + l] : 0u;
        unsigned rw2 = (cnt >= 2 && l < 21) ? rec2[(size_t)srt[st + 1] * 24 + l] : 0u;
        unsigned rw3 = (cnt >= 3 && l < 21) ? rec2[(size_t)srt[st + 2] * 24 + l] : 0u;
        float a0 = 0.f, a1 = 0.f, den = 0.f;
        for (int j = 0; j <= cnt; ++j) {
            float asv = __uint_as_float((unsigned)__shfl((int)rw0, 20, 32));
            float w = __expf(leaky(asv + ad));
            a0 = fmaf(w, bfLo(rw0), a0);
            a1 = fmaf(w, bfHi(rw0), a1);
            den += w;
            rw0 = rw1; rw1 = rw2; rw2 = rw3;
            rw3 = (j + 4 <= cnt && l < 21) ? rec2[(size_t)srt[st + j + 3] * 24 + l] : 0u;
        }
        float v0 = (l < 20) ? a0 / den + bb0 : -3.4e38f;
        float v1 = (l < 20) ? a1 / den + bb1 : -3.4e38f;
        float mx = fmaxf(v0, v1);
        #pragma unroll
        for (int k = 16; k >= 1; k >>= 1) mx = fmaxf(mx, __shfl_xor(mx, k, 32));
        float ex = (l < 20) ? __expf(v0 - mx) + __expf(v1 - mx) : 0.f;
        #pragma unroll
        for (int k = 16; k >= 1; k >>= 1) ex += __shfl_xor(ex, k, 32);
        float lse = mx + logf(ex);
        if (l < 20)
            ((float2*)(out + (size_t)node * 40))[l] = make_float2(v0 - lse, v1 - lse);
    }
}

extern "C" void kernel_launch(void* const* d_in, const int* in_sizes, int n_in,
                              void* d_out, int out_size, void* d_ws, size_t ws_size,
                              hipStream_t stream) {
    const float* x      = (const float*)d_in[0];
    const int*   e1_src = (const int*)d_in[1];
    const int*   e1_dst = (const int*)d_in[2];
    const int*   e2_src = (const int*)d_in[3];
    const int*   e2_dst = (const int*)d_in[4];
    const float* W1s    = (const float*)d_in[5];
    const float* W1d    = (const float*)d_in[6];
    const float* att1s  = (const float*)d_in[7];
    const float* att1d  = (const float*)d_in[8];
    const float* b1     = (const float*)d_in[9];
    const float* W2s    = (const float*)d_in[10];
    const float* W2d    = (const float*)d_in[11];
    const float* att2s  = (const float*)d_in[12];
    const float* att2d  = (const float*)d_in[13];
    const float* b2     = (const float*)d_in[14];
    float* out = (float*)d_out;

    // ---- workspace layout (4-byte words); everything is fully written before read ----
    float* wsbase = (float*)d_ws;
    size_t o = 0;
    int*      gcnt1 = (int*)(wsbase + o);      o += (size_t)NT1L * NB1;
    int*      gcnt2 = (int*)(wsbase + o);      o += (size_t)NT2L * NB2;
    unsigned* bin1  = (unsigned*)(wsbase + o); o += (size_t)NT1L * NB1 * SUBCAP;
    unsigned* bin2  = (unsigned*)(wsbase + o); o += (size_t)NT2L * NB2 * SUBCAP;
    unsigned* rec1  = (unsigned*)(wsbase + o); o += (size_t)N0 * 16;
    float*    a_d1  = (float*)(wsbase + o);    o += (size_t)N1 * 2;
    unsigned* rec2  = (unsigned*)(wsbase + o); o += (size_t)N1 * 24;

    k1_kernel<<<NTB + BPJ, 256, 0, stream>>>(
        x, W1s, W1d, att1s, att1d, e1_src, e1_dst, e2_src, e2_dst,
        rec1, a_d1, gcnt1, bin1, gcnt2, bin2);

    k2_kernel<<<NB1, 512, 0, stream>>>(gcnt1, bin1, rec1, a_d1, b1,
                                       W2s, W2d, att2s, att2d, rec2);

    k3_kernel<<<NB2, 1024, 0, stream>>>(gcnt2, bin2, rec2, b2, out);
}

// Round 22
// 112.640 us; speedup vs baseline: 1.0381x; 1.0381x over previous
//
#include <hip/hip_runtime.h>
#include <hip/hip_bf16.h>

// ---- problem constants ----
constexpr int N0 = 400000, N1 = 75000, N2 = 15000;
constexpr int E1 = 1200000, E2 = 240000;
constexpr int NC = 40;
constexpr float NEG_SLOPE = 0.2f;

// buckets (aggregation granularity)
constexpr int BK1 = 128;                     // dst nodes per bucket, layer 1
constexpr int NB1 = (N1 + BK1 - 1) / BK1;    // 586
constexpr int CAPB1 = 2432;                  // per-bucket total cap (mean 2048, +8.5 sigma)
constexpr int BK2 = 32;                      // dst nodes per bucket, layer 2
constexpr int NB2 = (N2 + BK2 - 1) / BK2;    // 469
constexpr int CAPB2 = 704;                   // mean 512, +8.5 sigma

// single-pass tile-private binning
constexpr int TILE = 4096;                   // edges per binning block
constexpr int NT1L = (E1 + TILE - 1) / TILE; // 293
constexpr int NT2L = (E2 + TILE - 1) / TILE; // 59
constexpr int NTB = NT1L + NT2L;             // 352 binning blocks
constexpr int SUBCAP = 32;                   // per (tile,bucket) cap
constexpr int BPJ = (N0 + 255) / 256;        // 1563 projection blocks (256 nodes each)

using f32x4 = __attribute__((ext_vector_type(4))) float;
using s16x8 = __attribute__((ext_vector_type(8))) short;   // 8 bf16 (4 VGPRs)

__device__ __forceinline__ float leaky(float v) { return v > 0.f ? v : NEG_SLOPE * v; }

// v_cvt_pk_bf16_f32: D[15:0]=bf16(lo), D[31:16]=bf16(hi) (no builtin on gfx950)
__device__ __forceinline__ unsigned cvtpk(float lo, float hi) {
    unsigned r;
    asm("v_cvt_pk_bf16_f32 %0, %1, %2" : "=v"(r) : "v"(lo), "v"(hi));
    return r;
}

// RNE pack of two floats into a bf16x2 word (VALU fallback, cold paths)
__device__ __forceinline__ unsigned bf16pair(float lo, float hi) {
    unsigned a = __float_as_uint(lo), b = __float_as_uint(hi);
    a = (a + 0x7FFFu + ((a >> 16) & 1u)) >> 16;
    b = (b + 0x7FFFu + ((b >> 16) & 1u)) & 0xFFFF0000u;
    return a | b;
}
__device__ __forceinline__ float bfLo(unsigned w) { return __uint_as_float(w << 16); }
__device__ __forceinline__ float bfHi(unsigned w) { return __uint_as_float(w & 0xFFFF0000u); }

// ============ K1: single-pass binning + MFMA projection (coalesced via LDS stage) ============
// rec1[node] (16 words, 64B): w0..w7 bf16x2 hs1, w8/w9 fp32 a_s; w10..15 pad
__global__ __launch_bounds__(256) void k1_kernel(
    const float* __restrict__ x,
    const float* __restrict__ W1s, const float* __restrict__ W1d,
    const float* __restrict__ att1s, const float* __restrict__ att1d,
    const int* __restrict__ e1s, const int* __restrict__ e1d,
    const int* __restrict__ e2s, const int* __restrict__ e2d,
    unsigned* __restrict__ rec1, float* __restrict__ a_d1,
    int* __restrict__ gcnt1, unsigned* __restrict__ bin1,
    int* __restrict__ gcnt2, unsigned* __restrict__ bin2)
{
    __shared__ float4 stage[4][272];           // 4 waves x (16 nodes x 17 padded slots)
    __shared__ float2 vds[64];                 // proj blocks touching N1 only
    int* cur = (int*)stage;                    // binning path alias (2344B < 17408B)

    int bid = blockIdx.x;
    const int tid = threadIdx.x;
    if (bid < NTB) {
        // ---- binning: ONE pass, tile-private sub-bins, no global atomics ----
        const bool isL1 = bid < NT1L;
        const int t = isL1 ? bid : bid - NT1L;
        const int* es = isL1 ? e1s : e2s;
        const int* ed = isL1 ? e1d : e2d;
        const int nE = isL1 ? E1 : E2;
        const int nb = isL1 ? NB1 : NB2;
        const int shift = isL1 ? 7 : 5;        // log2(BK)
        const int lsh = isL1 ? 19 : 17;        // local-dst shift in payload
        int* gc = isL1 ? gcnt1 : gcnt2;
        unsigned* gbin = isL1 ? bin1 : bin2;
        const int base = t * TILE;
        const int lim = min(TILE, nE - base);

        for (int b = tid; b < nb; b += 256) cur[b] = 0;
        __syncthreads();
        for (int i = tid; i < lim; i += 256) {
            int s = es[base + i], d = ed[base + i];
            if (s != d) {                      // remove_self_loops
                int b = d >> shift;
                int pos = atomicAdd(&cur[b], 1);
                if (pos < SUBCAP)
                    gbin[((size_t)t * nb + b) * SUBCAP + pos] =
                        (unsigned)s | ((unsigned)(d & ((1 << shift) - 1)) << lsh);
            }
        }
        __syncthreads();
        for (int b = tid; b < nb; b += 256)    // plain stores, coalesced
            gc[(size_t)t * nb + b] = min(cur[b], SUBCAP);
        return;
    }
    // ---- MFMA projection: 4 tiles/wave, fully-coalesced loads via LDS transpose ----
    bid -= NTB;
    const int l  = tid & 63;
    const int nd = l & 15;           // node within tile (D col)
    const int kg = l >> 4;           // k-group / channel quad
    const int wv = tid >> 6;
    const int nodeBase = bid * 256;
    const bool hasN1 = nodeBase < N1;

    if (hasN1) {                     // vd (att1d folded into W1d) -> LDS
        if (tid < 64) {
            float d0 = 0.f, d1 = 0.f;
            const float* wr = W1d + (size_t)tid * 16;
            #pragma unroll
            for (int cc = 0; cc < 8; ++cc) {
                d0 = fmaf(wr[cc], att1d[cc], d0);
                d1 = fmaf(wr[8 + cc], att1d[8 + cc], d1);
            }
            vds[tid] = make_float2(d0, d1);
        }
        __syncthreads();
    }

    // W1s fragment: lane holds W[k=(8kg..)+j][col=nd] (L1-hot, amortized over 64 nodes)
    s16x8 bf0, bf1;
    {
        union { unsigned u[4]; s16x8 v; } t0, t1;
        #pragma unroll
        for (int q = 0; q < 4; ++q) {
            t0.u[q] = cvtpk(W1s[(8 * kg + 2 * q) * 16 + nd],
                            W1s[(8 * kg + 2 * q + 1) * 16 + nd]);
            t1.u[q] = cvtpk(W1s[(32 + 8 * kg + 2 * q) * 16 + nd],
                            W1s[(32 + 8 * kg + 2 * q + 1) * 16 + nd]);
        }
        bf0 = t0.v; bf1 = t1.v;
    }
    float att4[4];
    #pragma unroll
    for (int r = 0; r < 4; ++r) att4[r] = att1s[4 * kg + r];

    float4* st = stage[wv];
    const int wslot = (l >> 4);      // node-subgroup for staging writes
    const int wlane = (l & 15);      // slot for staging writes

    #pragma unroll
    for (int t = 0; t < 4; ++t) {
        const int tile0 = nodeBase + wv * 64 + t * 16;
        if (tile0 >= N0) break;      // N0 % 16 == 0: tiles are full or absent

        // ---- coalesced load: 4 instrs, each 1KB contiguous (16 full lines) ----
        const float4* xg = (const float4*)x + (size_t)tile0 * 16;
        float4 v0 = xg[0 * 64 + l];
        float4 v1 = xg[1 * 64 + l];
        float4 v2 = xg[2 * 64 + l];
        float4 v3 = xg[3 * 64 + l];

        // ---- LDS transpose (padded: 17 slots/node; 2-way bank alias = free) ----
        st[(0 * 4 + wslot) * 17 + wlane] = v0;
        st[(1 * 4 + wslot) * 17 + wlane] = v1;
        st[(2 * 4 + wslot) * 17 + wlane] = v2;
        st[(3 * 4 + wslot) * 17 + wlane] = v3;
        // same-wave RAW: compiler inserts lgkmcnt wait; no barrier needed
        float4 p0 = st[nd * 17 + 2 * kg];
        float4 p1 = st[nd * 17 + 2 * kg + 1];
        float4 p2 = st[nd * 17 + 8 + 2 * kg];
        float4 p3 = st[nd * 17 + 8 + 2 * kg + 1];

        const int node = tile0 + nd;

        union { unsigned u[4]; s16x8 v; } a0, a1;
        a0.u[0] = cvtpk(p0.x, p0.y); a0.u[1] = cvtpk(p0.z, p0.w);
        a0.u[2] = cvtpk(p1.x, p1.y); a0.u[3] = cvtpk(p1.z, p1.w);
        a1.u[0] = cvtpk(p2.x, p2.y); a1.u[1] = cvtpk(p2.z, p2.w);
        a1.u[2] = cvtpk(p3.x, p3.y); a1.u[3] = cvtpk(p3.z, p3.w);

        f32x4 acc = {0.f, 0.f, 0.f, 0.f};
        acc = __builtin_amdgcn_mfma_f32_16x16x32_bf16(bf0, a0.v, acc, 0, 0, 0);
        acc = __builtin_amdgcn_mfma_f32_16x16x32_bf16(bf1, a1.v, acc, 0, 0, 0);
        // lane(kg,nd): hs[node][4kg+r] in acc[r]

        float p = acc[0] * att4[0];
        p = fmaf(acc[1], att4[1], p);
        p = fmaf(acc[2], att4[2], p);
        p = fmaf(acc[3], att4[3], p);
        p += __shfl_xor(p, 16, 64);
        float q = __shfl_xor(p, 32, 64);

        unsigned* rp = rec1 + (size_t)node * 16;
        uint2 hw;
        hw.x = cvtpk(acc[0], acc[1]);
        hw.y = cvtpk(acc[2], acc[3]);
        *(uint2*)(rp + 2 * kg) = hw;
        if (kg == 0)
            *(uint4*)(rp + 8) = make_uint4(__float_as_uint(p), __float_as_uint(q), 0u, 0u);
        else if (kg == 1)
            *(uint4*)(rp + 12) = make_uint4(0u, 0u, 0u, 0u);

        if (hasN1 && node < N1) {              // a_d1 = x . vd (LDS table)
            float xv8[16] = {p0.x, p0.y, p0.z, p0.w, p1.x, p1.y, p1.z, p1.w,
                             p2.x, p2.y, p2.z, p2.w, p3.x, p3.y, p3.z, p3.w};
            float pd0 = 0.f, pd1 = 0.f;
            #pragma unroll
            for (int j = 0; j < 8; ++j) {
                float2 v = vds[8 * kg + j];
                pd0 = fmaf(xv8[j], v.x, pd0);
                pd1 = fmaf(xv8[j], v.y, pd1);
            }
            #pragma unroll
            for (int j = 0; j < 8; ++j) {
                float2 v = vds[32 + 8 * kg + j];
                pd0 = fmaf(xv8[8 + j], v.x, pd0);
                pd1 = fmaf(xv8[8 + j], v.y, pd1);
            }
            pd0 += __shfl_xor(pd0, 16, 64); pd0 += __shfl_xor(pd0, 32, 64);
            pd1 += __shfl_xor(pd1, 16, 64); pd1 += __shfl_xor(pd1, 32, 64);
            if (kg == 0)
                ((float2*)a_d1)[node] = make_float2(pd0, pd1);
        }
    }
}

// ============ K2: sort + DUAL-CHAIN node-major aggregate + fused proj2 ============
// rec2[node] (24 words, 96B): w0..w19 bf16x2 hs2, w20 a_s2, w21 a_d2
__global__ __launch_bounds__(512) void k2_kernel(
    const int* __restrict__ gcnt1, const unsigned* __restrict__ bin1,
    const unsigned* __restrict__ rec1, const float* __restrict__ a_d1,
    const float* __restrict__ b1,
    const float* __restrict__ W2s, const float* __restrict__ W2d,
    const float* __restrict__ att2s, const float* __restrict__ att2d,
    unsigned* __restrict__ rec2)
{
    __shared__ unsigned raw[CAPB1];
    __shared__ unsigned srt[CAPB1];
    __shared__ int cnts[NT1L], pfx[NT1L + 1];
    __shared__ int hist[BK1], start[BK1 + 1];
    __shared__ float w2sl[640], va[16], vd[16];
    __shared__ float h1s[BK1][17];

    const int b = blockIdx.x, tid = threadIdx.x;
    const int d0 = b * BK1;
    const int nN = min(BK1, N1 - d0);

    for (int i = tid; i < 640; i += 512) w2sl[i] = W2s[i];
    if (tid < BK1) hist[tid] = 0;
    if (tid >= 128 && tid < 144) {            // fold att2 into W2 columns
        int k = tid - 128;
        float sa = 0.f, sd = 0.f;
        for (int cc = 0; cc < 40; ++cc) {
            sa = fmaf(W2s[k * 40 + cc], att2s[cc], sa);
            sd = fmaf(W2d[k * 40 + cc], att2d[cc], sd);
        }
        va[k] = sa; vd[k] = sd;
    }
    for (int i = tid; i < NT1L; i += 512) cnts[i] = gcnt1[(size_t)i * NB1 + b];
    __syncthreads();
    // exclusive scan over 293 tile counts (wave 0, shfl_up)
    if (tid < 64) {
        int carry = 0;
        #pragma unroll
        for (int s = 0; s < (NT1L + 63) / 64; ++s) {
            int idx = s * 64 + tid;
            int v = (idx < NT1L) ? cnts[idx] : 0;
            int xv = v;
            #pragma unroll
            for (int d = 1; d < 64; d <<= 1) {
                int t2 = __shfl_up(xv, d, 64);
                if (tid >= d) xv += t2;
            }
            if (idx < NT1L) pfx[idx] = carry + xv - v;
            carry += __shfl(xv, 63, 64);
        }
        if (tid == 0) pfx[NT1L] = carry;
    }
    __syncthreads();
    // gather chunks -> raw, histogram by local dst
    for (int j = tid; j < NT1L * SUBCAP; j += 512) {
        int t = j >> 5, p = j & (SUBCAP - 1);
        if (p < cnts[t]) {
            int dst = pfx[t] + p;
            if (dst < CAPB1) {
                unsigned pay = bin1[((size_t)t * NB1 + b) * SUBCAP + p];
                raw[dst] = pay;
                atomicAdd(&hist[pay >> 19], 1);
            }
        }
    }
    __syncthreads();
    if (tid == 0) {
        int a = 0;
        for (int k = 0; k < BK1; ++k) { start[k] = a; a += hist[k]; }
        start[BK1] = a;
    }
    __syncthreads();
    if (tid < BK1) hist[tid] = start[tid];    // cursor
    __syncthreads();
    const int total = min(pfx[NT1L], CAPB1);
    for (int i = tid; i < total; i += 512) {
        unsigned p = raw[i];
        int pos = atomicAdd(&hist[p >> 19], 1);
        srt[pos] = p & 0x7FFFFu;
    }
    __syncthreads();

    // ---- DUAL-CHAIN node-major aggregation: group g handles nodes (n, n+64) ----
    const int g = tid >> 4, c = tid & 15, h = c >> 3;
    const int wbase = tid & 48;
    const int wmap = (c < 8) ? c : (8 + ((c >> 2) & 1));
    for (int n0 = g; n0 < 64; n0 += 32) {
        const int nA = n0, nB = n0 + 64;
        const bool vB = nB < nN;               // nA < 64 <= nN always
        const int nodeA = d0 + nA, nodeB = d0 + min(nB, nN - 1);
        const float adA = a_d1[(size_t)nodeA * 2 + h];
        const float adB = a_d1[(size_t)nodeB * 2 + h];
        const int stA = start[nA], cntA = start[nA + 1] - stA;
        const int stB = vB ? start[nB] : 0;
        const int cntB = vB ? (start[nB + 1] - stB) : -1;

        // 3-deep prefetch per chain (j=0 is self)
        unsigned rwA0 = rec1[(size_t)nodeA * 16 + wmap];
        unsigned rwA1 = (cntA >= 1) ? rec1[(size_t)srt[stA] * 16 + wmap] : 0u;
        unsigned rwA2 = (cntA >= 2) ? rec1[(size_t)srt[stA + 1] * 16 + wmap] : 0u;
        unsigned rwB0 = vB ? rec1[(size_t)nodeB * 16 + wmap] : 0u;
        unsigned rwB1 = (cntB >= 1) ? rec1[(size_t)srt[stB] * 16 + wmap] : 0u;
        unsigned rwB2 = (cntB >= 2) ? rec1[(size_t)srt[stB + 1] * 16 + wmap] : 0u;

        float accA = 0.f, denA = 0.f, accB = 0.f, denB = 0.f;
        const int mx = max(cntA, cntB);
        for (int j = 0; j <= mx; ++j) {
            // chain A step (w forced to 0 past cntA; shuffles stay convergent)
            {
                float asv = __uint_as_float((unsigned)__shfl((int)rwA0, wbase + 8 + 4 * h, 64));
                unsigned chw = (unsigned)__shfl((int)rwA0, wbase + (c >> 1), 64);
                float hv = (c & 1) ? bfHi(chw) : bfLo(chw);
                float w = (j <= cntA) ? __expf(leaky(asv + adA)) : 0.f;
                accA = fmaf(w, hv, accA);
                denA += w;
            }
            // chain B step
            {
                float asv = __uint_as_float((unsigned)__shfl((int)rwB0, wbase + 8 + 4 * h, 64));
                unsigned chw = (unsigned)__shfl((int)rwB0, wbase + (c >> 1), 64);
                float hv = (c & 1) ? bfHi(chw) : bfLo(chw);
                float w = (j <= cntB) ? __expf(leaky(asv + adB)) : 0.f;
                accB = fmaf(w, hv, accB);
                denB += w;
            }
            rwA0 = rwA1; rwA1 = rwA2;
            rwA2 = (j + 3 <= cntA) ? rec1[(size_t)srt[stA + j + 2] * 16 + wmap] : 0u;
            rwB0 = rwB1; rwB1 = rwB2;
            rwB2 = (j + 3 <= cntB) ? rec1[(size_t)srt[stB + j + 2] * 16 + wmap] : 0u;
        }
        {
            float v = accA / denA + b1[c];
            h1s[nA][c] = v > 0.f ? v : (__expf(v) - 1.f);    // ELU
        }
        if (vB) {
            float v = accB / denB + b1[c];
            h1s[nB][c] = v > 0.f ? v : (__expf(v) - 1.f);
        }
    }
    __syncthreads();
    // fused proj2 -> rec2
    for (int i = tid; i < nN * 24; i += 512) {
        int nn = i / 24, w = i - nn * 24;
        unsigned* rp = rec2 + (size_t)(d0 + nn) * 24;
        if (w < 20) {
            int c0 = 2 * w, c1 = c0 + 1;
            float s0 = 0.f, s1 = 0.f;
            #pragma unroll
            for (int k = 0; k < 16; ++k) {
                float hk = h1s[nn][k];
                s0 = fmaf(hk, w2sl[k * 40 + c0], s0);
                s1 = fmaf(hk, w2sl[k * 40 + c1], s1);
            }
            rp[w] = bf16pair(s0, s1);
        } else if (w < 22) {
            const float* vv = (w == 20) ? va : vd;
            float s = 0.f;
            #pragma unroll
            for (int k = 0; k < 16; ++k) s = fmaf(h1s[nn][k], vv[k], s);
            rp[w] = __float_as_uint(s);
        }
    }
}

// ============ K3: gather tile-chunks + sort + 32-lane-group aggregate + log_softmax ============
__global__ __launch_bounds__(1024) void k3_kernel(
    const int* __restrict__ gcnt2, const unsigned* __restrict__ bin2,
    const unsigned* __restrict__ rec2, const float* __restrict__ b2,
    float* __restrict__ out)
{
    __shared__ unsigned raw[CAPB2];
    __shared__ unsigned srt[CAPB2];
    __shared__ int cnts[NT2L], pfx[NT2L + 1];
    __shared__ int hist[BK2], start[BK2 + 1];

    const int b = blockIdx.x, tid = threadIdx.x;
    const int d0 = b * BK2;
    const int nN = min(BK2, N2 - d0);

    if (tid < BK2) hist[tid] = 0;
    if (tid < NT2L) cnts[tid] = gcnt2[(size_t)tid * NB2 + b];
    __syncthreads();
    if (tid < 64) {                            // scan over 59 counts (one wave)
        int v = (tid < NT2L) ? cnts[tid] : 0;
        int xv = v;
        #pragma unroll
        for (int d = 1; d < 64; d <<= 1) {
            int t2 = __shfl_up(xv, d, 64);
            if (tid >= d) xv += t2;
        }
        if (tid < NT2L) pfx[tid] = xv - v;
        if (tid == NT2L - 1) pfx[NT2L] = xv;
    }
    __syncthreads();
    for (int j = tid; j < NT2L * SUBCAP; j += 1024) {
        int t = j >> 5, p = j & (SUBCAP - 1);
        if (p < cnts[t]) {
            int dst = pfx[t] + p;
            if (dst < CAPB2) {
                unsigned pay = bin2[((size_t)t * NB2 + b) * SUBCAP + p];
                raw[dst] = pay;
                atomicAdd(&hist[pay >> 17], 1);
            }
        }
    }
    __syncthreads();
    if (tid == 0) {
        int a = 0;
        for (int k = 0; k < BK2; ++k) { start[k] = a; a += hist[k]; }
        start[BK2] = a;
    }
    __syncthreads();
    if (tid < BK2) hist[tid] = start[tid];
    __syncthreads();
    const int total = min(pfx[NT2L], CAPB2);
    for (int i = tid; i < total; i += 1024) {
        unsigned p = raw[i];
        int pos = atomicAdd(&hist[p >> 17], 1);
        srt[pos] = p & 0x1FFFFu;
    }
    __syncthreads();

    // 32 groups of 32 lanes; lane l holds record word l (channels 2l,2l+1 for l<20)
    const int g = tid >> 5, l = tid & 31;
    const float bb0 = (l < 20) ? b2[2 * l] : 0.f;
    const float bb1 = (l < 20) ? b2[2 * l + 1] : 0.f;
    for (int n = g; n < nN; n += 32) {
        const int node = d0 + n;
        const int st = start[n], cnt = start[n + 1] - start[n];
        unsigned rw0 = (l < 22) ? rec2[(size_t)node * 24 + l] : 0u;          // self
        const float ad = __uint_as_float((unsigned)__shfl((int)rw0, 21, 32));
        unsigned rw1 = (cnt >= 1 && l < 21) ? rec2[(size_t)srt[st] * 24 + l] : 0u;
        unsigned rw2 = (cnt >= 2 && l < 21) ? rec2[(size_t)srt[st + 1] * 24 + l] : 0u;
        unsigned rw3 = (cnt >= 3 && l < 21) ? rec2[(size_t)srt[st + 2] * 24 + l] : 0u;
        float a0 = 0.f, a1 = 0.f, den = 0.f;
        for (int j = 0; j <= cnt; ++j) {
            float asv = __uint_as_float((unsigned)__shfl((int)rw0, 20, 32));
            float w = __expf(leaky(asv + ad));
            a0 = fmaf(w, bfLo(rw0), a0);
            a1 = fmaf(w, bfHi(rw0), a1);
            den += w;
            rw0 = rw1; rw1 = rw2; rw2 = rw3;
            rw3 = (j + 4 <= cnt && l < 21) ? rec2[(size_t)srt[st + j + 3] * 24 + l] : 0u;
        }
        float v0 = (l < 20) ? a0 / den + bb0 : -3.4e38f;
        float v1 = (l < 20) ? a1 / den + bb1 : -3.4e38f;
        float mx = fmaxf(v0, v1);
        #pragma unroll
        for (int k = 16; k >= 1; k >>= 1) mx = fmaxf(mx, __shfl_xor(mx, k, 32));
        float ex = (l < 20) ? __expf(v0 - mx) + __expf(v1 - mx) : 0.f;
        #pragma unroll
        for (int k = 16; k >= 1; k >>= 1) ex += __shfl_xor(ex, k, 32);
        float lse = mx + logf(ex);
        if (l < 20)
            ((float2*)(out + (size_t)node * 40))[l] = make_float2(v0 - lse, v1 - lse);
    }
}

extern "C" void kernel_launch(void* const* d_in, const int* in_sizes, int n_in,
                              void* d_out, int out_size, void* d_ws, size_t ws_size,
                              hipStream_t stream) {
    const float* x      = (const float*)d_in[0];
    const int*   e1_src = (const int*)d_in[1];
    const int*   e1_dst = (const int*)d_in[2];
    const int*   e2_src = (const int*)d_in[3];
    const int*   e2_dst = (const int*)d_in[4];
    const float* W1s    = (const float*)d_in[5];
    const float* W1d    = (const float*)d_in[6];
    const float* att1s  = (const float*)d_in[7];
    const float* att1d  = (const float*)d_in[8];
    const float* b1     = (const float*)d_in[9];
    const float* W2s    = (const float*)d_in[10];
    const float* W2d    = (const float*)d_in[11];
    const float* att2s  = (const float*)d_in[12];
    const float* att2d  = (const float*)d_in[13];
    const float* b2     = (const float*)d_in[14];
    float* out = (float*)d_out;

    // ---- workspace layout (4-byte words); everything is fully written before read ----
    float* wsbase = (float*)d_ws;
    size_t o = 0;
    int*      gcnt1 = (int*)(wsbase + o);      o += (size_t)NT1L * NB1;
    int*      gcnt2 = (int*)(wsbase + o);      o += (size_t)NT2L * NB2;
    unsigned* bin1  = (unsigned*)(wsbase + o); o += (size_t)NT1L * NB1 * SUBCAP;
    unsigned* bin2  = (unsigned*)(wsbase + o); o += (size_t)NT2L * NB2 * SUBCAP;
    unsigned* rec1  = (unsigned*)(wsbase + o); o += (size_t)N0 * 16;
    float*    a_d1  = (float*)(wsbase + o);    o += (size_t)N1 * 2;
    unsigned* rec2  = (unsigned*)(wsbase + o); o += (size_t)N1 * 24;

    k1_kernel<<<NTB + BPJ, 256, 0, stream>>>(
        x, W1s, W1d, att1s, att1d, e1_src, e1_dst, e2_src, e2_dst,
        rec1, a_d1, gcnt1, bin1, gcnt2, bin2);

    k2_kernel<<<NB1, 512, 0, stream>>>(gcnt1, bin1, rec1, a_d1, b1,
                                       W2s, W2d, att2s, att2d, rec2);

    k3_kernel<<<NB2, 1024, 0, stream>>>(gcnt2, bin2, rec2, b2, out);
}